// Round 10
// baseline (146.003 us; speedup 1.0000x reference)
//
#include <hip/hip_runtime.h>
#include <hip/hip_bf16.h>

#define B 16
#define L 128
#define H 256
#define H2 512
#define P 16
#define EPSF 1e-8f
#define LDSTR2 264   // shorts per 256-col bf16 LDS row (+8 pad)

typedef __attribute__((ext_vector_type(8))) short short8;
typedef __attribute__((ext_vector_type(4))) short short4v;
typedef __attribute__((ext_vector_type(4))) float f32x4;

__device__ __forceinline__ short f2bf(float x) {
    unsigned u = __builtin_bit_cast(unsigned, x);
    u += 0x7fffu + ((u >> 16) & 1u);   // RNE; inputs finite
    return (short)(u >> 16);
}
__device__ __forceinline__ float bf2f(short s) {
    unsigned u = ((unsigned)(unsigned short)s) << 16;
    return __builtin_bit_cast(float, u);
}
__device__ __forceinline__ short8 pack8(float4 x, float4 y) {
    short8 s;
    s[0] = f2bf(x.x); s[1] = f2bf(x.y); s[2] = f2bf(x.z); s[3] = f2bf(x.w);
    s[4] = f2bf(y.x); s[5] = f2bf(y.y); s[6] = f2bf(y.z); s[7] = f2bf(y.w);
    return s;
}
__device__ __forceinline__ float dot4(float4 v) {
    return v.x * v.x + v.y * v.y + v.z * v.z + v.w * v.w;
}
__device__ __forceinline__ float4 mul4(float4 a, float4 b) {
    return make_float4(a.x * b.x, a.y * b.y, a.z * b.z, a.w * b.w);
}

// ---- K0: prep — bf16 copies, exact norms, w-folded consistent norms --------
// Grid (2048, 2): (row-global, src). 64 thr (1 wave); lane owns cols l*4 per dir.
__global__ void __launch_bounds__(64) k_prep(
        const float* __restrict__ q1, const float* __restrict__ q2,
        const float* __restrict__ W,
        short* __restrict__ q1b, short* __restrict__ q2b,
        float* __restrict__ nex,   // [(src*2+dir)][2048] exact norms
        float* __restrict__ nW) {  // [((src*2+dir)*16+p)][2048] w-folded bf16-consistent
    int row = blockIdx.x;
    int src = blockIdx.y;
    int l = threadIdx.x;
    const float* base = (src ? q2 : q1) + (size_t)row * H2;
    short* qb = (src ? q2b : q1b) + (size_t)row * H2;

    float4 xf = *(const float4*)(base + l * 4);
    float4 xb = *(const float4*)(base + H + l * 4);
    short4v sf = { f2bf(xf.x), f2bf(xf.y), f2bf(xf.z), f2bf(xf.w) };
    short4v sb = { f2bf(xb.x), f2bf(xb.y), f2bf(xb.z), f2bf(xb.w) };
    *(short4v*)(qb + l * 4) = sf;
    *(short4v*)(qb + H + l * 4) = sb;

    float nf = dot4(xf), nb = dot4(xb);
#pragma unroll
    for (int off = 1; off < 64; off <<= 1) {
        nf += __shfl_xor(nf, off);
        nb += __shfl_xor(nb, off);
    }
    if (l == 0) {
        nex[(src * 2 + 0) * 2048 + row] = sqrtf(nf);
        nex[(src * 2 + 1) * 2048 + row] = sqrtf(nb);
    }
#pragma unroll
    for (int dir = 0; dir < 2; dir++) {
        float4 x = dir ? xb : xf;
#pragma unroll
        for (int p = 0; p < P; p++) {
            float4 w4 = *(const float4*)(W + ((size_t)(2 + dir) * P + p) * H + l * 4);
            float4 e = mul4(x, w4);
            float v0 = bf2f(f2bf(e.x)), v1 = bf2f(f2bf(e.y));
            float v2 = bf2f(f2bf(e.z)), v3 = bf2f(f2bf(e.w));
            float s = v0 * v0 + v1 * v1 + v2 * v2 + v3 * v3;
#pragma unroll
            for (int off = 1; off < 64; off <<= 1) s += __shfl_xor(s, off);
            if (l == 0)
                nW[(((size_t)src * 2 + dir) * P + p) * 2048 + row] = sqrtf(s);
        }
    }
}

// ---- K1: attention — bf16 LDS tiles staged row-contiguously ----------------
// Grid (B*2, 8): (b,dir) x m-tile(16). 256 thr / 4 waves; wave w = cols w*32..+31.
__global__ void __launch_bounds__(256, 2) k_att_v4(
        const short* __restrict__ q1b, const short* __restrict__ q2b,
        const float* __restrict__ nex,
        float* __restrict__ att_fw, float* __restrict__ att_bw,
        float* __restrict__ attsum) {
    int bd = blockIdx.x;
    int b = bd >> 1, dir = bd & 1;
    int m0 = blockIdx.y * 16;
    int t = threadIdx.x;
    int wave = t >> 6, l = t & 63;
    int q = l >> 4, coll = l & 15;
    int n0 = wave * 32;
    size_t bL = (size_t)b * L;

    __shared__ short As[16 * LDSTR2];
    __shared__ short Bs[128 * LDSTR2];
    __shared__ float part[4][16];

    // stage: each wave-instr covers 2 full rows (lane i: row_local i>>5, shorts (i&31)*8)
    int rsub = l >> 5, c8 = (l & 31) * 8;
#pragma unroll
    for (int j = 0; j < 2; j++) {
        int r16 = wave * 4 + j * 2 + rsub;
        short8 v = *(const short8*)(q1b + (bL + m0 + r16) * H2 + dir * H + c8);
        *(short8*)(As + r16 * LDSTR2 + c8) = v;
    }
#pragma unroll
    for (int j = 0; j < 16; j++) {
        int r = wave * 32 + j * 2 + rsub;
        short8 v = *(const short8*)(q2b + (bL + r) * H2 + dir * H + c8);
        *(short8*)(Bs + r * LDSTR2 + c8) = v;
    }
    __syncthreads();

    f32x4 acc[2];
    acc[0] = (f32x4){0.f, 0.f, 0.f, 0.f};
    acc[1] = (f32x4){0.f, 0.f, 0.f, 0.f};
#pragma unroll
    for (int ks = 0; ks < 8; ks++) {
        int koff = ks * 32 + q * 8;
        short8 af = *(const short8*)(As + coll * LDSTR2 + koff);
        short8 b0 = *(const short8*)(Bs + (n0 + coll) * LDSTR2 + koff);
        short8 b1 = *(const short8*)(Bs + (n0 + 16 + coll) * LDSTR2 + koff);
        acc[0] = __builtin_amdgcn_mfma_f32_16x16x32_bf16(af, b0, acc[0], 0, 0, 0);
        acc[1] = __builtin_amdgcn_mfma_f32_16x16x32_bf16(af, b1, acc[1], 0, 0, 0);
    }

    const float* n1a = nex + (size_t)dir * 2048 + bL;        // q1 exact
    const float* n2a = nex + (size_t)(2 + dir) * 2048 + bL;  // q2 exact
    float n1v[4];
#pragma unroll
    for (int r = 0; r < 4; r++) n1v[r] = n1a[m0 + q * 4 + r];

    float* attout = dir ? att_bw : att_fw;
    float rsum[4] = {0.f, 0.f, 0.f, 0.f};
#pragma unroll
    for (int nt = 0; nt < 2; nt++) {
        int col = n0 + nt * 16 + coll;
        float n2v = n2a[col];
#pragma unroll
        for (int r = 0; r < 4; r++) {
            float den = n1v[r] * n2v;
            den = den > EPSF ? den : EPSF;
            float a = acc[nt][r] / den;
            attout[(bL + m0 + q * 4 + r) * L + col] = a;
            rsum[r] += a;
        }
    }
    if (dir == 0) {
#pragma unroll
        for (int off = 1; off < 16; off <<= 1)
#pragma unroll
            for (int r = 0; r < 4; r++)
                rsum[r] += __shfl_xor(rsum[r], off, 16);
        if (coll == 0)
#pragma unroll
            for (int r = 0; r < 4; r++)
                part[wave][q * 4 + r] = rsum[r];
        __syncthreads();
        if (t < 16)
            attsum[bL + m0 + t] = part[0][t] + part[1][t] + part[2][t] + part[3][t];
    }
}

// ---- K2: weighted mean (bw uses fw row-sum, per reference) + max of att*q2 --
__global__ void __launch_bounds__(256) k_meanmax_v3(
        const float* __restrict__ q2,
        const float* __restrict__ att_fw, const float* __restrict__ att_bw,
        const float* __restrict__ attsum,
        float* __restrict__ mean_fw, float* __restrict__ mean_bw,
        float* __restrict__ maxat_fw, float* __restrict__ maxat_bw) {
    int bd = blockIdx.x;
    int b = bd >> 1, dir = bd & 1;
    int i0 = blockIdx.y * 4;
    int t = threadIdx.x;
    int wave = t >> 6, l = t & 63;
    size_t bL = (size_t)b * L;

    __shared__ float at[4][L];
    __shared__ float Ss[4];
    __shared__ f32x4 red[4][64][4];

    const float* att = dir ? att_bw : att_fw;
    for (int v = t; v < 4 * L; v += 256)
        at[v >> 7][v & 127] = att[(bL + i0 + (v >> 7)) * L + (v & 127)];
    if (t < 4) {
        float s = attsum[bL + i0 + t];
        Ss[t] = s > EPSF ? s : EPSF;
    }
    __syncthreads();

    f32x4 sum[4], mx[4];
#pragma unroll
    for (int r = 0; r < 4; r++) {
        sum[r] = (f32x4){0.f, 0.f, 0.f, 0.f};
        mx[r] = (f32x4){-INFINITY, -INFINITY, -INFINITY, -INFINITY};
    }
    const float* q2b = q2 + bL * H2 + dir * H;
    for (int jj = 0; jj < 32; jj++) {
        int j = wave * 32 + jj;
        float4 c = *(const float4*)(q2b + (size_t)j * H2 + l * 4);
#pragma unroll
        for (int r = 0; r < 4; r++) {
            float w = at[r][j];
            f32x4 v = { w * c.x, w * c.y, w * c.z, w * c.w };
            sum[r] += v;
            mx[r][0] = fmaxf(mx[r][0], v[0]);
            mx[r][1] = fmaxf(mx[r][1], v[1]);
            mx[r][2] = fmaxf(mx[r][2], v[2]);
            mx[r][3] = fmaxf(mx[r][3], v[3]);
        }
    }
    float* meanout = dir ? mean_bw : mean_fw;
    float* maxout = dir ? maxat_bw : maxat_fw;
    for (int rr = 0; rr < 2; rr++) {
        __syncthreads();
        red[wave][l][0] = sum[rr * 2];
        red[wave][l][1] = mx[rr * 2];
        red[wave][l][2] = sum[rr * 2 + 1];
        red[wave][l][3] = mx[rr * 2 + 1];
        __syncthreads();
        if (t < 128) {
            int r2 = t >> 6;
            int lane = t & 63;
            f32x4 s = red[0][lane][r2 * 2];
            f32x4 m = red[0][lane][r2 * 2 + 1];
            for (int w = 1; w < 4; w++) {
                s += red[w][lane][r2 * 2];
                f32x4 m2 = red[w][lane][r2 * 2 + 1];
                m[0] = fmaxf(m[0], m2[0]);
                m[1] = fmaxf(m[1], m2[1]);
                m[2] = fmaxf(m[2], m2[2]);
                m[3] = fmaxf(m[3], m2[3]);
            }
            int row = i0 + rr * 2 + r2;
            float inv = 1.f / Ss[rr * 2 + r2];
            size_t o = (bL + row) * H + lane * 4;
            *(f32x4*)(meanout + o) = s * inv;
            *(f32x4*)(maxout + o) = m;
        }
    }
}

// ---- K3: six cos_full pieces, fp32, float4 loads ---------------------------
// Grid (B*16, 6): (b, 8 i-rows, piece). 256 thr: p = t>>4, lane l owns h in [l*16,l*16+16).
__global__ void __launch_bounds__(256) k_cosfull_v4(
        const float* __restrict__ q1, const float* __restrict__ q2,
        const float* __restrict__ mean_fw, const float* __restrict__ mean_bw,
        const float* __restrict__ maxat_fw, const float* __restrict__ maxat_bw,
        const float* __restrict__ W, float* __restrict__ out) {
    int bg = blockIdx.x;
    int b = bg >> 4;
    int i0 = (bg & 15) * 8;
    int piece = blockIdx.y;
    int t = threadIdx.x;
    int p = t >> 4, l = t & 15;
    size_t bL = (size_t)b * L;

    int widx, colb, dir, cstride;
    const float* cptr;
    switch (piece) {
        case 0: widx = 0; colb = 0;   dir = 0; cptr = q2 + (bL + L - 1) * H2;  cstride = 0; break;
        case 1: widx = 1; colb = 16;  dir = 1; cptr = q2 + bL * H2 + H;        cstride = 0; break;
        case 2: widx = 4; colb = 64;  dir = 0; cptr = mean_fw + bL * H;        cstride = H; break;
        case 3: widx = 5; colb = 80;  dir = 1; cptr = mean_bw + bL * H;        cstride = H; break;
        case 4: widx = 6; colb = 96;  dir = 0; cptr = maxat_fw + bL * H;       cstride = H; break;
        default: widx = 7; colb = 112; dir = 1; cptr = maxat_bw + bL * H;      cstride = H; break;
    }
    const float* wrow = W + ((size_t)widx * P + p) * H + l * 16;
    float4 wq[4];
#pragma unroll
    for (int c = 0; c < 4; c++) {
        float4 w4 = *(const float4*)(wrow + c * 4);
        wq[c] = mul4(w4, w4);
    }
    for (int ii = 0; ii < 8; ii++) {
        int i = i0 + ii;
        const float* r1 = q1 + (bL + i) * H2 + dir * H + l * 16;
        const float* crow = cptr + (size_t)i * cstride + l * 16;
        float num = 0, na = 0, nc = 0;
#pragma unroll
        for (int c = 0; c < 4; c++) {
            float4 a = *(const float4*)(r1 + c * 4);
            float4 cc = *(const float4*)(crow + c * 4);
            num += a.x * cc.x * wq[c].x + a.y * cc.y * wq[c].y
                 + a.z * cc.z * wq[c].z + a.w * cc.w * wq[c].w;
            na  += a.x * a.x * wq[c].x + a.y * a.y * wq[c].y
                 + a.z * a.z * wq[c].z + a.w * a.w * wq[c].w;
            nc  += cc.x * cc.x * wq[c].x + cc.y * cc.y * wq[c].y
                 + cc.z * cc.z * wq[c].z + cc.w * cc.w * wq[c].w;
        }
        for (int off = 8; off; off >>= 1) {
            num += __shfl_down(num, off, 16);
            na  += __shfl_down(na,  off, 16);
            nc  += __shfl_down(nc,  off, 16);
        }
        if (l == 0) {
            float den = sqrtf(na) * sqrtf(nc);
            den = den > EPSF ? den : EPSF;
            out[(bL + i) * 128 + colb + p] = num / den;
        }
    }
}

// ---- K4: cos_maxpool — B staged once row-contiguously, norms from prep -----
// Grid (B*2, P, 2): (b,dir) x p x m-half. 256 thr, 4 waves (16 A-rows each).
__global__ void __launch_bounds__(256, 2) k_maxpool_v4(
        const float* __restrict__ q1, const float* __restrict__ q2,
        const float* __restrict__ W, const float* __restrict__ nW,
        float* __restrict__ out) {
    int bd = blockIdx.x;
    int b = bd >> 1, dir = bd & 1;
    int p = blockIdx.y;
    int t = threadIdx.x;
    int wave = t >> 6, l = t & 63;
    int q = l >> 4, coll = l & 15;
    int m0 = blockIdx.z * 64 + wave * 16;
    size_t bL = (size_t)b * L;

    __shared__ short Bs[128 * LDSTR2];
    __shared__ float wf[H];

    const float* wbase = W + ((size_t)(2 + dir) * P + p) * H;
    if (t < 64)
        *(float4*)(wf + t * 4) = *(const float4*)(wbase + t * 4);

    // stage B: wave-instr = 1 full row (lane l covers cols l*4), w folded from register
    float4 wreg = *(const float4*)(wbase + l * 4);
    const float* q2b = q2 + bL * H2 + dir * H;
#pragma unroll 8
    for (int j = 0; j < 32; j++) {
        int r = wave * 32 + j;
        float4 v = *(const float4*)(q2b + (size_t)r * H2 + l * 4);
        float4 e = mul4(v, wreg);
        short4v s = { f2bf(e.x), f2bf(e.y), f2bf(e.z), f2bf(e.w) };
        *(short4v*)(Bs + r * LDSTR2 + l * 4) = s;
    }
    __syncthreads();

    f32x4 acc[8];
#pragma unroll
    for (int nt = 0; nt < 8; nt++) acc[nt] = (f32x4){0.f, 0.f, 0.f, 0.f};

    const float* arow = q1 + (bL + m0 + coll) * H2 + dir * H;
#pragma unroll
    for (int ks = 0; ks < 8; ks++) {
        int koff = ks * 32 + q * 8;
        float4 a0 = *(const float4*)(arow + koff);
        float4 a1 = *(const float4*)(arow + koff + 4);
        float4 w0 = *(const float4*)(wf + koff);
        float4 w1 = *(const float4*)(wf + koff + 4);
        short8 af = pack8(mul4(a0, w0), mul4(a1, w1));
#pragma unroll
        for (int nt = 0; nt < 8; nt++) {
            short8 bf = *(const short8*)(Bs + (nt * 16 + coll) * LDSTR2 + koff);
            acc[nt] = __builtin_amdgcn_mfma_f32_16x16x32_bf16(af, bf, acc[nt], 0, 0, 0);
        }
    }

    const float* naW = nW + (((size_t)0 * 2 + dir) * P + p) * 2048 + bL;  // q1 side
    const float* ncW = nW + (((size_t)1 * 2 + dir) * P + p) * 2048 + bL;  // q2 side
    float nar[4];
#pragma unroll
    for (int r = 0; r < 4; r++) nar[r] = naW[m0 + q * 4 + r];
    float rmax[4] = {-INFINITY, -INFINITY, -INFINITY, -INFINITY};
#pragma unroll
    for (int nt = 0; nt < 8; nt++) {
        float ncv = ncW[nt * 16 + coll];
#pragma unroll
        for (int r = 0; r < 4; r++) {
            float den = fmaxf(nar[r] * ncv, EPSF);
            rmax[r] = fmaxf(rmax[r], acc[nt][r] / den);
        }
    }
#pragma unroll
    for (int off = 1; off < 16; off <<= 1)
#pragma unroll
        for (int r = 0; r < 4; r++)
            rmax[r] = fmaxf(rmax[r], __shfl_xor(rmax[r], off, 16));
    if (coll == 0)
#pragma unroll
        for (int r = 0; r < 4; r++)
            out[(bL + m0 + q * 4 + r) * 128 + 32 + dir * 16 + p] = rmax[r];
}

extern "C" void kernel_launch(void* const* d_in, const int* in_sizes, int n_in,
                              void* d_out, int out_size, void* d_ws, size_t ws_size,
                              hipStream_t stream) {
    const float* q1 = (const float*)d_in[0];
    const float* q2 = (const float*)d_in[1];
    const float* W  = (const float*)d_in[2];
    float* out = (float*)d_out;

    float* ws = (float*)d_ws;
    float* attsum = ws;                               // 2048
    float* att_fw = attsum + 2048;                    // 262144
    float* att_bw = att_fw + (size_t)B * L * L;
    float* mean_fw = att_bw + (size_t)B * L * L;      // B*L*H each
    float* mean_bw = mean_fw + (size_t)B * L * H;
    float* maxat_fw = mean_bw + (size_t)B * L * H;
    float* maxat_bw = maxat_fw + (size_t)B * L * H;
    float* nex = maxat_bw + (size_t)B * L * H;        // 4*2048
    float* nW  = nex + 4 * 2048;                      // 2*2*16*2048
    short* q1b = (short*)(nW + (size_t)2 * 2 * P * 2048);
    short* q2b = q1b + (size_t)2048 * H2;

    hipMemsetAsync(attsum, 0, 2048 * sizeof(float), stream);
    k_prep<<<dim3(2048, 2), 64, 0, stream>>>(q1, q2, W, q1b, q2b, nex, nW);
    k_maxpool_v4<<<dim3(B * 2, P, 2), 256, 0, stream>>>(q1, q2, W, nW, out);
    k_att_v4<<<dim3(B * 2, 8), 256, 0, stream>>>(q1b, q2b, nex, att_fw, att_bw, attsum);
    k_meanmax_v3<<<dim3(B * 2, 32), 256, 0, stream>>>(q2, att_fw, att_bw, attsum,
                                                      mean_fw, mean_bw, maxat_fw, maxat_bw);
    k_cosfull_v4<<<dim3(B * 16, 6), 256, 0, stream>>>(q1, q2, mean_fw, mean_bw,
                                                      maxat_fw, maxat_bw, W, out);
}